// Round 1
// baseline (952.812 us; speedup 1.0000x reference)
//
#include <hip/hip_runtime.h>

// VQ-VAE Vector Quantizer: N=65536 rows, K=4096 codes, D=64, fp32.
// out layout (float): [0,N*D) z_q_st | [ND] vq | [ND+1] cb | [ND+2] cm |
//                     [ND+3, ND+3+N) indices (as float) | [ND+3+N] perplexity | [ND+4+N] active
// ws layout: e2[K] float | counts[K] int | loss accum float

constexpr int N = 65536;
constexpr int K = 4096;
constexpr int D = 64;
constexpr int TK = 128;   // codes staged in LDS per tile (32 KB)

__global__ __launch_bounds__(256) void prep_kernel(const float* __restrict__ emb,
                                                   float* __restrict__ e2,
                                                   int* __restrict__ counts,
                                                   float* __restrict__ loss) {
  int k = blockIdx.x * 256 + threadIdx.x;
  if (k < K) {
    const float4* ep = (const float4*)(emb + (size_t)k * D);
    float s0 = 0.f, s1 = 0.f, s2 = 0.f, s3 = 0.f;
#pragma unroll
    for (int i = 0; i < 16; ++i) {
      float4 e = ep[i];
      s0 = fmaf(e.x, e.x, s0);
      s1 = fmaf(e.y, e.y, s1);
      s2 = fmaf(e.z, e.z, s2);
      s3 = fmaf(e.w, e.w, s3);
    }
    e2[k] = (s0 + s1) + (s2 + s3);
    counts[k] = 0;
  }
  if (blockIdx.x == 0 && threadIdx.x == 0) *loss = 0.0f;
}

__global__ __launch_bounds__(256) void vq_main(const float* __restrict__ z,
                                               const float* __restrict__ emb,
                                               const float* __restrict__ e2,
                                               float* __restrict__ out,
                                               int* __restrict__ counts,
                                               float* __restrict__ loss) {
  __shared__ float lds_e[TK * D];   // 32 KB
  __shared__ float lds_e2[TK];
  __shared__ float red[4];

  const int tid = threadIdx.x;
  const int n = blockIdx.x * 256 + tid;

  // Load this thread's z row into registers (64 VGPRs).
  float4 zr[16];
  {
    const float4* zp = (const float4*)(z + (size_t)n * D);
#pragma unroll
    for (int i = 0; i < 16; ++i) zr[i] = zp[i];
  }

  // z2 = sum(z*z). (e2[k] ~ 1e-9 << 0.5*ulp(z2~64), so (z2+e2) rounds back to
  // z2 in fp32 exactly as in the reference; a +-1ulp difference in z2 shifts
  // all dist values uniformly within the binade -> tie structure preserved.)
  float z2;
  {
    float s0 = 0.f, s1 = 0.f, s2 = 0.f, s3 = 0.f;
#pragma unroll
    for (int i = 0; i < 16; ++i) {
      s0 = fmaf(zr[i].x, zr[i].x, s0);
      s1 = fmaf(zr[i].y, zr[i].y, s1);
      s2 = fmaf(zr[i].z, zr[i].z, s2);
      s3 = fmaf(zr[i].w, zr[i].w, s3);
    }
    z2 = (s0 + s1) + (s2 + s3);
  }

  float best = 3.4e38f;
  int bidx = 0;

  for (int t = 0; t < K / TK; ++t) {
    __syncthreads();
    {
      const float4* ep = (const float4*)(emb + (size_t)t * TK * D);
      float4* lp = (float4*)lds_e;
#pragma unroll
      for (int i = 0; i < (TK * D / 4) / 256; ++i)
        lp[tid + i * 256] = ep[tid + i * 256];
      if (tid < TK) lds_e2[tid] = e2[t * TK + tid];
    }
    __syncthreads();

#pragma unroll 4
    for (int k = 0; k < TK; ++k) {
      const float4* er = (const float4*)(lds_e + k * D);  // wave-broadcast reads
      float s0 = 0.f, s1 = 0.f, s2 = 0.f, s3 = 0.f;
#pragma unroll
      for (int i = 0; i < 16; ++i) {
        float4 e = er[i];
        s0 = fmaf(zr[i].x, e.x, s0);
        s1 = fmaf(zr[i].y, e.y, s1);
        s2 = fmaf(zr[i].z, e.z, s2);
        s3 = fmaf(zr[i].w, e.w, s3);
      }
      float dot = (s0 + s1) + (s2 + s3);
      // Replicate reference fp32 rounding: (z2 + e2) - 2*dot
      float dist = (z2 + lds_e2[k]) - 2.0f * dot;
      int kk = t * TK + k;
      if (dist < best) { best = dist; bidx = kk; }   // strict <: first-index tie-break
    }
  }

  // Epilogue: index, counts, z_q gather, z_q_st, loss partial.
  out[(size_t)N * D + 3 + n] = (float)bidx;
  atomicAdd(&counts[bidx], 1);

  const float4* qp = (const float4*)(emb + (size_t)bidx * D);
  float4* op = (float4*)(out + (size_t)n * D);
  float lsum = 0.f;
#pragma unroll
  for (int i = 0; i < 16; ++i) {
    float4 q = qp[i];
    float4 zz = zr[i];
    float dx = q.x - zz.x, dy = q.y - zz.y, dz = q.z - zz.z, dw = q.w - zz.w;
    lsum = fmaf(dx, dx, lsum);
    lsum = fmaf(dy, dy, lsum);
    lsum = fmaf(dz, dz, lsum);
    lsum = fmaf(dw, dw, lsum);
    // z_q_st = z + (z_q - z), replicated op-for-op (not bitwise == z_q)
    float4 r;
    r.x = zz.x + dx; r.y = zz.y + dy; r.z = zz.z + dz; r.w = zz.w + dw;
    op[i] = r;
  }

  // block reduction of loss partial
#pragma unroll
  for (int off = 32; off > 0; off >>= 1) lsum += __shfl_down(lsum, off);
  if ((tid & 63) == 0) red[tid >> 6] = lsum;
  __syncthreads();
  if (tid == 0) atomicAdd(loss, (red[0] + red[1]) + (red[2] + red[3]));
}

__global__ __launch_bounds__(256) void finalize_kernel(const int* __restrict__ counts,
                                                       const float* __restrict__ loss,
                                                       float* __restrict__ out) {
  const int tid = threadIdx.x;
  double ent = 0.0;
  int active = 0;
  for (int k = tid; k < K; k += 256) {
    int c = counts[k];
    float p = (float)c / 65536.0f;
    if (c > 0) active++;
    ent += (double)(p * logf(p + 1e-10f));
  }
#pragma unroll
  for (int off = 32; off > 0; off >>= 1) {
    ent += __shfl_down(ent, off);
    active += __shfl_down(active, off);
  }
  __shared__ double ered[4];
  __shared__ int ared[4];
  if ((tid & 63) == 0) { ered[tid >> 6] = ent; ared[tid >> 6] = active; }
  __syncthreads();
  if (tid == 0) {
    double e = (ered[0] + ered[1]) + (ered[2] + ered[3]);
    int a = (ared[0] + ared[1]) + (ared[2] + ared[3]);
    float mean = *loss / (float)((size_t)N * D);
    float cb = mean;
    float cm = mean;
    float vq = cb + 0.25f * cm;
    size_t base = (size_t)N * D;
    out[base + 0] = vq;
    out[base + 1] = cb;
    out[base + 2] = cm;
    out[base + 3 + N] = (float)exp(-e);
    out[base + 4 + N] = (float)a;
  }
}

extern "C" void kernel_launch(void* const* d_in, const int* in_sizes, int n_in,
                              void* d_out, int out_size, void* d_ws, size_t ws_size,
                              hipStream_t stream) {
  const float* z = (const float*)d_in[0];
  const float* emb = (const float*)d_in[1];
  float* out = (float*)d_out;

  float* e2 = (float*)d_ws;
  int* counts = (int*)((char*)d_ws + (size_t)K * sizeof(float));
  float* loss = (float*)((char*)d_ws + (size_t)2 * K * sizeof(float));

  prep_kernel<<<K / 256, 256, 0, stream>>>(emb, e2, counts, loss);
  vq_main<<<N / 256, 256, 0, stream>>>(z, emb, e2, out, counts, loss);
  finalize_kernel<<<1, 256, 0, stream>>>(counts, loss, out);
}

// Round 2
// 656.158 us; speedup vs baseline: 1.4521x; 1.4521x over previous
//
#include <hip/hip_runtime.h>

// VQ-VAE Vector Quantizer: N=65536 rows, K=4096 codes, D=64, fp32.
// out layout (float): [0,N*D) z_q_st | [ND] vq | [ND+1] cb | [ND+2] cm |
//                     [ND+3, ND+3+N) indices (as float) | [ND+3+N] perplexity | [ND+4+N] active
// ws layout: e2[K] | counts[K] int | loss | pbest[S*N] | pidx[S*N] int

constexpr int N = 65536;
constexpr int K = 4096;
constexpr int D = 64;
constexpr int TK = 128;   // codes staged in LDS per tile (32 KB)
constexpr int S = 4;      // K-split factor: grid = 1024 blocks -> 4 blocks/CU, 16 waves/CU
constexpr int KS = K / S; // 1024 codes per slice

__global__ __launch_bounds__(256) void prep_kernel(const float* __restrict__ emb,
                                                   float* __restrict__ e2,
                                                   int* __restrict__ counts,
                                                   float* __restrict__ loss) {
  int k = blockIdx.x * 256 + threadIdx.x;
  if (k < K) {
    const float4* ep = (const float4*)(emb + (size_t)k * D);
    float s0 = 0.f, s1 = 0.f, s2 = 0.f, s3 = 0.f;
#pragma unroll
    for (int i = 0; i < 16; ++i) {
      float4 e = ep[i];
      s0 = fmaf(e.x, e.x, s0);
      s1 = fmaf(e.y, e.y, s1);
      s2 = fmaf(e.z, e.z, s2);
      s3 = fmaf(e.w, e.w, s3);
    }
    e2[k] = (s0 + s1) + (s2 + s3);
    counts[k] = 0;
  }
  if (blockIdx.x == 0 && threadIdx.x == 0) *loss = 0.0f;
}

// Scan one K-slice for 256 rows per block. grid = (N/256, S).
__global__ __launch_bounds__(256) void vq_scan(const float* __restrict__ z,
                                               const float* __restrict__ emb,
                                               const float* __restrict__ e2,
                                               float* __restrict__ pbest,
                                               int* __restrict__ pidx) {
  __shared__ float lds_e[TK * D];   // 32 KB
  __shared__ float lds_e2[TK];

  const int tid = threadIdx.x;
  const int n = blockIdx.x * 256 + tid;
  const int s = blockIdx.y;
  const int k0 = s * KS;

  float4 zr[16];
  {
    const float4* zp = (const float4*)(z + (size_t)n * D);
#pragma unroll
    for (int i = 0; i < 16; ++i) zr[i] = zp[i];
  }

  // z2 identical across slices (same instruction sequence, same data).
  float z2;
  {
    float s0 = 0.f, s1 = 0.f, s2 = 0.f, s3 = 0.f;
#pragma unroll
    for (int i = 0; i < 16; ++i) {
      s0 = fmaf(zr[i].x, zr[i].x, s0);
      s1 = fmaf(zr[i].y, zr[i].y, s1);
      s2 = fmaf(zr[i].z, zr[i].z, s2);
      s3 = fmaf(zr[i].w, zr[i].w, s3);
    }
    z2 = (s0 + s1) + (s2 + s3);
  }

  float best = 3.4e38f;
  int bidx = k0;

  for (int t = 0; t < KS / TK; ++t) {
    __syncthreads();
    {
      const float4* ep = (const float4*)(emb + (size_t)(k0 + t * TK) * D);
      float4* lp = (float4*)lds_e;
#pragma unroll
      for (int i = 0; i < (TK * D / 4) / 256; ++i)
        lp[tid + i * 256] = ep[tid + i * 256];
      if (tid < TK) lds_e2[tid] = e2[k0 + t * TK + tid];
    }
    __syncthreads();

#pragma unroll 4
    for (int k = 0; k < TK; ++k) {
      const float4* er = (const float4*)(lds_e + k * D);  // wave-broadcast, conflict-free
      float s0 = 0.f, s1 = 0.f, s2 = 0.f, s3 = 0.f;
#pragma unroll
      for (int i = 0; i < 16; ++i) {
        float4 e = er[i];
        s0 = fmaf(zr[i].x, e.x, s0);
        s1 = fmaf(zr[i].y, e.y, s1);
        s2 = fmaf(zr[i].z, e.z, s2);
        s3 = fmaf(zr[i].w, e.w, s3);
      }
      float dot = (s0 + s1) + (s2 + s3);
      // Reference fp32 rounding replicated: (z2 + e2) - 2*dot
      float dist = (z2 + lds_e2[k]) - 2.0f * dot;
      int kk = k0 + t * TK + k;
      if (dist < best) { best = dist; bidx = kk; }  // strict <: first-index within slice
    }
  }

  pbest[(size_t)s * N + n] = best;
  pidx[(size_t)s * N + n] = bidx;
}

// Combine slices (ascending s => ascending k => first-index tie-break preserved
// with strict <), then gather/losses/counts/index write.
__global__ __launch_bounds__(256) void vq_epilogue(const float* __restrict__ z,
                                                   const float* __restrict__ emb,
                                                   const float* __restrict__ pbest,
                                                   const int* __restrict__ pidx,
                                                   float* __restrict__ out,
                                                   int* __restrict__ counts,
                                                   float* __restrict__ loss) {
  __shared__ float red[4];
  const int tid = threadIdx.x;
  const int n = blockIdx.x * 256 + tid;

  float best = pbest[n];
  int bidx = pidx[n];
#pragma unroll
  for (int s = 1; s < S; ++s) {
    float d = pbest[(size_t)s * N + n];
    if (d < best) { best = d; bidx = pidx[(size_t)s * N + n]; }
  }

  out[(size_t)N * D + 3 + n] = (float)bidx;
  atomicAdd(&counts[bidx], 1);

  const float4* zp = (const float4*)(z + (size_t)n * D);
  const float4* qp = (const float4*)(emb + (size_t)bidx * D);
  float4* op = (float4*)(out + (size_t)n * D);
  float lsum = 0.f;
#pragma unroll
  for (int i = 0; i < 16; ++i) {
    float4 q = qp[i];
    float4 zz = zp[i];
    float dx = q.x - zz.x, dy = q.y - zz.y, dz = q.z - zz.z, dw = q.w - zz.w;
    lsum = fmaf(dx, dx, lsum);
    lsum = fmaf(dy, dy, lsum);
    lsum = fmaf(dz, dz, lsum);
    lsum = fmaf(dw, dw, lsum);
    // z_q_st = z + (z_q - z), replicated op-for-op
    float4 r;
    r.x = zz.x + dx; r.y = zz.y + dy; r.z = zz.z + dz; r.w = zz.w + dw;
    op[i] = r;
  }

#pragma unroll
  for (int off = 32; off > 0; off >>= 1) lsum += __shfl_down(lsum, off);
  if ((tid & 63) == 0) red[tid >> 6] = lsum;
  __syncthreads();
  if (tid == 0) atomicAdd(loss, (red[0] + red[1]) + (red[2] + red[3]));
}

__global__ __launch_bounds__(256) void finalize_kernel(const int* __restrict__ counts,
                                                       const float* __restrict__ loss,
                                                       float* __restrict__ out) {
  const int tid = threadIdx.x;
  double ent = 0.0;
  int active = 0;
  for (int k = tid; k < K; k += 256) {
    int c = counts[k];
    float p = (float)c / 65536.0f;
    if (c > 0) active++;
    ent += (double)(p * logf(p + 1e-10f));
  }
#pragma unroll
  for (int off = 32; off > 0; off >>= 1) {
    ent += __shfl_down(ent, off);
    active += __shfl_down(active, off);
  }
  __shared__ double ered[4];
  __shared__ int ared[4];
  if ((tid & 63) == 0) { ered[tid >> 6] = ent; ared[tid >> 6] = active; }
  __syncthreads();
  if (tid == 0) {
    double e = (ered[0] + ered[1]) + (ered[2] + ered[3]);
    int a = (ared[0] + ared[1]) + (ared[2] + ared[3]);
    float mean = *loss / (float)((size_t)N * D);
    float cb = mean;
    float cm = mean;
    float vq = cb + 0.25f * cm;
    size_t base = (size_t)N * D;
    out[base + 0] = vq;
    out[base + 1] = cb;
    out[base + 2] = cm;
    out[base + 3 + N] = (float)exp(-e);
    out[base + 4 + N] = (float)a;
  }
}

extern "C" void kernel_launch(void* const* d_in, const int* in_sizes, int n_in,
                              void* d_out, int out_size, void* d_ws, size_t ws_size,
                              hipStream_t stream) {
  const float* z = (const float*)d_in[0];
  const float* emb = (const float*)d_in[1];
  float* out = (float*)d_out;

  char* w = (char*)d_ws;
  float* e2 = (float*)w;                         w += (size_t)K * sizeof(float);
  int* counts = (int*)w;                         w += (size_t)K * sizeof(int);
  float* loss = (float*)w;                       w += 256;  // keep alignment
  float* pbest = (float*)w;                      w += (size_t)S * N * sizeof(float);
  int* pidx = (int*)w;

  prep_kernel<<<K / 256, 256, 0, stream>>>(emb, e2, counts, loss);
  vq_scan<<<dim3(N / 256, S), 256, 0, stream>>>(z, emb, e2, pbest, pidx);
  vq_epilogue<<<N / 256, 256, 0, stream>>>(z, emb, pbest, pidx, out, counts, loss);
  finalize_kernel<<<1, 256, 0, stream>>>(counts, loss, out);
}

// Round 3
// 546.835 us; speedup vs baseline: 1.7424x; 1.1999x over previous
//
#include <hip/hip_runtime.h>

// VQ-VAE Vector Quantizer: N=65536 rows, K=4096 codes, D=64, fp32.
// R3: e-operand via SCALAR path (address_space(4) -> s_load) instead of LDS.
// All 64 lanes of a wave process the same code k => e[k][*] is wave-uniform,
// lives in SGPRs, v_fmac_f32 reads it as the 1-allowed-SGPR operand.
// FMA sequence per (row,code) is bit-identical to the R2 passing kernel
// (quad-split partials by d mod 4, ascending d, (s0+s1)+(s2+s3), then
// dist = (z2 + e2[k]) - 2*dot) => identical indices, absmax 0 by construction.
//
// out layout (float): [0,N*D) z_q_st | [ND] vq | [ND+1] cb | [ND+2] cm |
//                     [ND+3, ND+3+N) indices | [ND+3+N] perplexity | [ND+4+N] active

constexpr int N = 65536;
constexpr int K = 4096;
constexpr int D = 64;
constexpr int S = 8;      // K-split: grid = 2048 blocks
constexpr int KS = K / S; // 512 codes per slice

typedef float vf16 __attribute__((ext_vector_type(16)));
typedef const __attribute__((address_space(4))) vf16* cvf16p;
typedef const __attribute__((address_space(4))) float* cfp;

__global__ __launch_bounds__(256) void prep_kernel(const float* __restrict__ emb,
                                                   float* __restrict__ e2,
                                                   int* __restrict__ counts,
                                                   float* __restrict__ loss) {
  int k = blockIdx.x * 256 + threadIdx.x;
  if (k < K) {
    const float4* ep = (const float4*)(emb + (size_t)k * D);
    float s0 = 0.f, s1 = 0.f, s2 = 0.f, s3 = 0.f;
#pragma unroll
    for (int i = 0; i < 16; ++i) {
      float4 e = ep[i];
      s0 = fmaf(e.x, e.x, s0);
      s1 = fmaf(e.y, e.y, s1);
      s2 = fmaf(e.z, e.z, s2);
      s3 = fmaf(e.w, e.w, s3);
    }
    e2[k] = (s0 + s1) + (s2 + s3);
    counts[k] = 0;
  }
  if (blockIdx.x == 0 && threadIdx.x == 0) *loss = 0.0f;
}

// Scan one K-slice for 256 rows per block. grid = (N/256, S). No LDS.
__global__ __launch_bounds__(256) void vq_scan(const float* __restrict__ z,
                                               const float* __restrict__ emb,
                                               const float* __restrict__ e2,
                                               float* __restrict__ pbest,
                                               int* __restrict__ pidx) {
  const int tid = threadIdx.x;
  const int n = blockIdx.x * 256 + tid;
  const int s = blockIdx.y;
  const int k0 = s * KS;

  // This lane's z row in 64 VGPRs.
  float4 zr[16];
  {
    const float4* zp = (const float4*)(z + (size_t)n * D);
#pragma unroll
    for (int i = 0; i < 16; ++i) zr[i] = zp[i];
  }

  // z2, same instruction sequence as R2 (quad-split, ascending d).
  float z2;
  {
    float s0 = 0.f, s1 = 0.f, s2 = 0.f, s3 = 0.f;
#pragma unroll
    for (int i = 0; i < 16; ++i) {
      s0 = fmaf(zr[i].x, zr[i].x, s0);
      s1 = fmaf(zr[i].y, zr[i].y, s1);
      s2 = fmaf(zr[i].z, zr[i].z, s2);
      s3 = fmaf(zr[i].w, zr[i].w, s3);
    }
    z2 = (s0 + s1) + (s2 + s3);
  }

  // Scalar-path pointers (constant address space -> s_load on uniform index).
  cvf16p ep = (cvf16p)(uintptr_t)(emb + (size_t)k0 * D);
  cfp e2p = (cfp)(uintptr_t)(e2 + k0);

  float best = 3.4e38f;
  int bidx = k0;

  for (int k = 0; k < KS; ++k) {
    // e[k][0:64] -> 4x s_load_dwordx16 into SGPRs (wave-uniform address).
    vf16 ev[4];
#pragma unroll
    for (int c = 0; c < 4; ++c) ev[c] = ep[(size_t)k * 4 + c];

    float s0 = 0.f, s1 = 0.f, s2 = 0.f, s3 = 0.f;
#pragma unroll
    for (int c = 0; c < 4; ++c) {
#pragma unroll
      for (int j = 0; j < 4; ++j) {
        // d = 16*c + 4*j + {0,1,2,3}; partial sN takes d % 4 == N, ascending d
        s0 = fmaf(zr[c * 4 + j].x, ev[c][4 * j + 0], s0);
        s1 = fmaf(zr[c * 4 + j].y, ev[c][4 * j + 1], s1);
        s2 = fmaf(zr[c * 4 + j].z, ev[c][4 * j + 2], s2);
        s3 = fmaf(zr[c * 4 + j].w, ev[c][4 * j + 3], s3);
      }
    }
    float dot = (s0 + s1) + (s2 + s3);
    float dist = (z2 + e2p[k]) - 2.0f * dot;   // reference fp32 rounding replicated
    if (dist < best) { best = dist; bidx = k0 + k; }  // strict <: first-index in slice
  }

  pbest[(size_t)s * N + n] = best;
  pidx[(size_t)s * N + n] = bidx;
}

// Combine slices (ascending s = ascending k => first-index tie-break preserved),
// then gather/losses/counts/index write.
__global__ __launch_bounds__(256) void vq_epilogue(const float* __restrict__ z,
                                                   const float* __restrict__ emb,
                                                   const float* __restrict__ pbest,
                                                   const int* __restrict__ pidx,
                                                   float* __restrict__ out,
                                                   int* __restrict__ counts,
                                                   float* __restrict__ loss) {
  __shared__ float red[4];
  const int tid = threadIdx.x;
  const int n = blockIdx.x * 256 + tid;

  float best = pbest[n];
  int bidx = pidx[n];
#pragma unroll
  for (int s = 1; s < S; ++s) {
    float d = pbest[(size_t)s * N + n];
    if (d < best) { best = d; bidx = pidx[(size_t)s * N + n]; }
  }

  out[(size_t)N * D + 3 + n] = (float)bidx;
  atomicAdd(&counts[bidx], 1);

  const float4* zp = (const float4*)(z + (size_t)n * D);
  const float4* qp = (const float4*)(emb + (size_t)bidx * D);
  float4* op = (float4*)(out + (size_t)n * D);
  float lsum = 0.f;
#pragma unroll
  for (int i = 0; i < 16; ++i) {
    float4 q = qp[i];
    float4 zz = zp[i];
    float dx = q.x - zz.x, dy = q.y - zz.y, dz = q.z - zz.z, dw = q.w - zz.w;
    lsum = fmaf(dx, dx, lsum);
    lsum = fmaf(dy, dy, lsum);
    lsum = fmaf(dz, dz, lsum);
    lsum = fmaf(dw, dw, lsum);
    // z_q_st = z + (z_q - z), replicated op-for-op
    float4 r;
    r.x = zz.x + dx; r.y = zz.y + dy; r.z = zz.z + dz; r.w = zz.w + dw;
    op[i] = r;
  }

#pragma unroll
  for (int off = 32; off > 0; off >>= 1) lsum += __shfl_down(lsum, off);
  if ((tid & 63) == 0) red[tid >> 6] = lsum;
  __syncthreads();
  if (tid == 0) atomicAdd(loss, (red[0] + red[1]) + (red[2] + red[3]));
}

__global__ __launch_bounds__(256) void finalize_kernel(const int* __restrict__ counts,
                                                       const float* __restrict__ loss,
                                                       float* __restrict__ out) {
  const int tid = threadIdx.x;
  double ent = 0.0;
  int active = 0;
  for (int k = tid; k < K; k += 256) {
    int c = counts[k];
    float p = (float)c / 65536.0f;
    if (c > 0) active++;
    ent += (double)(p * logf(p + 1e-10f));
  }
#pragma unroll
  for (int off = 32; off > 0; off >>= 1) {
    ent += __shfl_down(ent, off);
    active += __shfl_down(active, off);
  }
  __shared__ double ered[4];
  __shared__ int ared[4];
  if ((tid & 63) == 0) { ered[tid >> 6] = ent; ared[tid >> 6] = active; }
  __syncthreads();
  if (tid == 0) {
    double e = (ered[0] + ered[1]) + (ered[2] + ered[3]);
    int a = (ared[0] + ared[1]) + (ared[2] + ared[3]);
    float mean = *loss / (float)((size_t)N * D);
    float cb = mean;
    float cm = mean;
    float vq = cb + 0.25f * cm;
    size_t base = (size_t)N * D;
    out[base + 0] = vq;
    out[base + 1] = cb;
    out[base + 2] = cm;
    out[base + 3 + N] = (float)exp(-e);
    out[base + 4 + N] = (float)a;
  }
}

extern "C" void kernel_launch(void* const* d_in, const int* in_sizes, int n_in,
                              void* d_out, int out_size, void* d_ws, size_t ws_size,
                              hipStream_t stream) {
  const float* z = (const float*)d_in[0];
  const float* emb = (const float*)d_in[1];
  float* out = (float*)d_out;

  char* w = (char*)d_ws;
  float* e2 = (float*)w;                         w += (size_t)K * sizeof(float);
  int* counts = (int*)w;                         w += (size_t)K * sizeof(int);
  float* loss = (float*)w;                       w += 256;  // keep alignment
  float* pbest = (float*)w;                      w += (size_t)S * N * sizeof(float);
  int* pidx = (int*)w;

  prep_kernel<<<K / 256, 256, 0, stream>>>(emb, e2, counts, loss);
  vq_scan<<<dim3(N / 256, S), 256, 0, stream>>>(z, emb, e2, pbest, pidx);
  vq_epilogue<<<N / 256, 256, 0, stream>>>(z, emb, pbest, pidx, out, counts, loss);
  finalize_kernel<<<1, 256, 0, stream>>>(counts, loss, out);
}